// Round 18
// baseline (123.594 us; speedup 1.0000x reference)
//
#include <hip/hip_runtime.h>
#include <hip/hip_bf16.h>

typedef __bf16 bf16;
typedef __bf16 bf16x4 __attribute__((ext_vector_type(4)));
typedef __bf16 bf16x8 __attribute__((ext_vector_type(8)));
typedef float f32x4 __attribute__((ext_vector_type(4)));
typedef float f32x16 __attribute__((ext_vector_type(16)));

#define B_ 4
#define NE_ 1536
#define NR_ 512
#define N_ 2048
#define D_ 128
#define H_ 4
#define DH_ 32
#define P_ 2
#define M_ (B_*N_)      // 8192 rows total
#define NW_ (N_/32)     // 64 mask words per row
#define SK_ 4           // split-k chunks for attention
#define KCH_ (N_/SK_)   // 512 k per chunk
#define NIT_ (KCH_/64)  // 8 kv-tiles of 64 per chunk

__device__ __forceinline__ f32x4 mfma16(bf16x8 a, bf16x8 b, f32x4 c) {
    return __builtin_amdgcn_mfma_f32_16x16x32_bf16(a, b, c, 0, 0, 0);
}
__device__ __forceinline__ f32x16 mfma32(bf16x8 a, bf16x8 b, f32x16 c) {
    return __builtin_amdgcn_mfma_f32_32x32x16_bf16(a, b, c, 0, 0, 0);
}
__device__ __forceinline__ unsigned cvtpk(float lo, float hi) {
    unsigned r;
    asm("v_cvt_pk_bf16_f32 %0, %1, %2" : "=v"(r) : "v"(lo), "v"(hi));
    return r;
}
__device__ __forceinline__ void swap32(unsigned& a, unsigned& b) {
    asm("v_permlane32_swap_b32 %0, %1" : "+v"(a), "+v"(b));
}
__device__ __forceinline__ void gload16(const void* g, void* l) {
    __builtin_amdgcn_global_load_lds(
        (const __attribute__((address_space(1))) void*)g,
        (__attribute__((address_space(3))) void*)l, 16, 0, 0);
}

// fragment-major weight index: col c (out), k i, depth K.
__device__ __forceinline__ size_t fragidx(int c, int i, int K) {
    int nb = c >> 4, kc = i >> 5;
    int l = ((i >> 3) & 3) * 16 + (c & 15);
    return ((size_t)(nb * (K >> 5) + kc) * 64 + l) * 8 + (i & 7);
}

// ---------------- merged prep: QKV-p0 (direct f32) + mask-pack + repack -----
#define QKVB_ 768                // 128 m-tiles x 6 n-tiles
#define MKN_ (B_*N_*NW_)         // 524288 mask words
#define PPER_ (3*16384 + 16384 + 65536 + 65536 + 384)   // 196992
#define PRN_ (P_*PPER_)          // 393984
__global__ __launch_bounds__(256) void k_prep(
        const float* __restrict__ vents, const int* __restrict__ rels,
        const float* __restrict__ renc, const int* __restrict__ adj,
        const float* __restrict__ Wq, const float* __restrict__ Wk,
        const float* __restrict__ Wv, const float* __restrict__ Wo,
        const float* __restrict__ l1w, const float* __restrict__ l2w,
        const float* __restrict__ bq, const float* __restrict__ bk,
        const float* __restrict__ bv,
        unsigned int* __restrict__ mw,
        bf16* __restrict__ wqkvT, float* __restrict__ bqkv,
        bf16* __restrict__ woT, bf16* __restrict__ l1T,
        bf16* __restrict__ l2T,
        bf16* __restrict__ Qout, bf16* __restrict__ Kout,
        bf16* __restrict__ VTout) {
    const float SC = 0.25503330560513437f;     // (1/sqrt(32)) * log2(e)
    if (blockIdx.x < QKVB_) {
        int qb = blockIdx.x;
        int mt = qb / 6, nt = qb % 6;
        int lane = threadIdx.x & 63, wid = threadIdx.x >> 6;
        int wr = wid >> 1, wc = wid & 1;
        int m0 = mt * 64 + wr * 32;
        int n0 = nt * 64 + wc * 32;
        int lr = lane & 15, lg = lane >> 4;
        const float* srcA[2];
#pragma unroll
        for (int mi = 0; mi < 2; ++mi) {
            int row = m0 + mi * 16 + lr;
            int n = row & (N_ - 1), b = row >> 11;
            srcA[mi] = (n < NE_) ? vents + ((size_t)(b * NE_ + n)) * D_
                                 : renc + (size_t)rels[b * NR_ + (n - NE_)] * D_;
        }
        f32x4 acc[2][2];
#pragma unroll
        for (int mi = 0; mi < 2; ++mi)
#pragma unroll
            for (int ni = 0; ni < 2; ++ni)
                acc[mi][ni] = f32x4{0.f, 0.f, 0.f, 0.f};
        for (int k0 = 0; k0 < 128; k0 += 32) {
            bf16x8 a[2], bb[2];
#pragma unroll
            for (int mi = 0; mi < 2; ++mi) {
                float4 f0 = *(const float4*)(srcA[mi] + k0 + lg * 8);
                float4 f1 = *(const float4*)(srcA[mi] + k0 + lg * 8 + 4);
                bf16x8 v;
                v[0] = (bf16)f0.x; v[1] = (bf16)f0.y; v[2] = (bf16)f0.z; v[3] = (bf16)f0.w;
                v[4] = (bf16)f1.x; v[5] = (bf16)f1.y; v[6] = (bf16)f1.z; v[7] = (bf16)f1.w;
                a[mi] = v;
            }
#pragma unroll
            for (int ni = 0; ni < 2; ++ni) {
                int col = n0 + ni * 16 + lr;
                int which = col >> 7, c0 = col & 127;
                const float* W = which == 0 ? Wq : (which == 1 ? Wk : Wv);
                float sc = which == 0 ? SC : 1.f;
                bf16x8 v;
#pragma unroll
                for (int e = 0; e < 8; ++e)
                    v[e] = (bf16)(W[(size_t)(k0 + lg * 8 + e) * 128 + c0] * sc);
                bb[ni] = v;
            }
#pragma unroll
            for (int mi = 0; mi < 2; ++mi)
#pragma unroll
                for (int ni = 0; ni < 2; ++ni)
                    acc[mi][ni] = mfma16(a[mi], bb[ni], acc[mi][ni]);
        }
#pragma unroll
        for (int mi = 0; mi < 2; ++mi) {
#pragma unroll
            for (int ni = 0; ni < 2; ++ni) {
                int col = n0 + ni * 16 + lr;
                int which = col >> 7, c0 = col & 127;
                float bs = which == 0 ? bq[c0] * SC : (which == 1 ? bk[c0] : bv[c0]);
                int rowb = m0 + mi * 16 + lg * 4;
                if (which == 0) {
#pragma unroll
                    for (int r = 0; r < 4; ++r)
                        Qout[(size_t)(rowb + r) * D_ + c0] = (bf16)(acc[mi][ni][r] + bs);
                } else if (which == 1) {
#pragma unroll
                    for (int r = 0; r < 4; ++r)
                        Kout[(size_t)(rowb + r) * D_ + c0] = (bf16)(acc[mi][ni][r] + bs);
                } else {
                    int h = c0 >> 5, dh = c0 & 31;
                    int b = rowb >> 11, nn = rowb & (N_ - 1);
                    bf16x4 pk;
#pragma unroll
                    for (int r = 0; r < 4; ++r) pk[r] = (bf16)(acc[mi][ni][r] + bs);
                    *(bf16x4*)(VTout + ((size_t)(b * H_ + h) * DH_ + dh) * N_ + nn) = pk;
                }
            }
        }
        return;
    }
    int idx = (blockIdx.x - QKVB_) * 256 + threadIdx.x;
    if (idx < MKN_) {
        const int4* a = (const int4*)(adj + (size_t)idx * 32);
        unsigned int w = 0;
#pragma unroll
        for (int q = 0; q < 8; ++q) {
            int4 t = a[q];
            w |= (t.x != 0 ? 1u : 0u) << (q * 4 + 0);
            w |= (t.y != 0 ? 1u : 0u) << (q * 4 + 1);
            w |= (t.z != 0 ? 1u : 0u) << (q * 4 + 2);
            w |= (t.w != 0 ? 1u : 0u) << (q * 4 + 3);
        }
        mw[idx] = w;
        return;
    }
    idx -= MKN_;
    if (idx >= PRN_) return;
    int p = idx / PPER_;
    int r = idx % PPER_;
    if (r < 3 * 16384) {
        int which = r / 16384, e = r % 16384;
        int o = e >> 7, i = e & 127;
        const float* W = which == 0 ? Wq : (which == 1 ? Wk : Wv);
        float v = W[(size_t)(p * 128 + i) * 128 + o];
        if (which == 0) v *= SC;
        wqkvT[(size_t)p * 384 * 128 + fragidx(which * 128 + o, i, 128)] = (bf16)v;
    } else if ((r -= 3 * 16384) < 16384) {
        int o = r >> 7, i = r & 127;
        woT[(size_t)p * 16384 + fragidx(o, i, 128)] = (bf16)Wo[(size_t)(p * 128 + i) * 128 + o];
    } else if ((r -= 16384) < 65536) {
        int o = r >> 7, i = r & 127;          // o<512, i<128
        l1T[(size_t)p * 65536 + fragidx(o, i, 128)] = (bf16)l1w[(size_t)(p * 128 + i) * 512 + o];
    } else if ((r -= 65536) < 65536) {
        int o = r >> 9, i = r & 511;          // o<128, i<512
        l2T[(size_t)p * 65536 + fragidx(o, i, 512)] = (bf16)l2w[(size_t)(p * 512 + i) * 128 + o];
    } else {
        r -= 65536;
        float v = r < 128 ? bq[p * 128 + r] * SC
                          : (r < 256 ? bk[p * 128 + r - 128] : bv[p * 128 + r - 256]);
        bqkv[p * 384 + r] = v;
    }
}

// ---------------- fused flash attention (VAR=0 real; VAR=1 softmax-stub) ----
// VAR=1 keeps staging, mask LDS reads, QK^T (live via keep-alive), PV+ones
// MFMAs (fed live qf regs as fake P) -- deletes ALL softmax VALU. Its output
// is garbage; the real VAR=0 launch fully overwrites partO/partML afterward.
template <int VAR>
__global__ __launch_bounds__(256) void k_attn(
    const bf16* __restrict__ Q, const bf16* __restrict__ Kt,
    const bf16* __restrict__ VT, const unsigned int* __restrict__ mw,
    bf16* __restrict__ partO, float* __restrict__ partML) {
    __shared__ __align__(16) char kbuf[3][4096];   // [slot: m*2+hf][64 k][16B]
    __shared__ __align__(16) char vbuf[3][4096];   // [slot: kt'*2+hf][32 dh][16B]
    __shared__ __align__(16) unsigned mbuf[128][18];   // 9KB mask tile, padded
    int wid = threadIdx.x >> 6;
    int lane = threadIdx.x & 63;
    int ql = lane & 31, hf = lane >> 5;
    int qx = blockIdx.x;
    int bh = blockIdx.y;
    int kc = blockIdx.z;
    int b = bh >> 2, h = bh & 3;
    int qg = qx * 128 + wid * 32 + ql;
    const size_t bnD = (size_t)b * N_ * D_;

    const bf16* qp = Q + bnD + (size_t)qg * D_ + h * 32 + hf * 8;
    bf16x8 qf0 = *(const bf16x8*)(qp);
    bf16x8 qf1 = *(const bf16x8*)(qp + 16);

    // stage this block's 128 q-rows x 16 mask words into LDS
#pragma unroll
    for (int j = 0; j < 2; ++j) {
        int u = threadIdx.x + 256 * j;               // 0..511
        int row = u >> 2, sub = u & 3;
        uint4 mv = *(const uint4*)(mw + ((size_t)b * N_ + qx * 128 + row) * NW_
                                      + kc * (KCH_ / 32) + sub * 4);
        uint2 lo; lo.x = mv.x; lo.y = mv.y;
        uint2 hi; hi.x = mv.z; hi.y = mv.w;
        *(uint2*)(&mbuf[row][sub * 4]) = lo;
        *(uint2*)(&mbuf[row][sub * 4 + 2]) = hi;
    }
    asm volatile("s_waitcnt lgkmcnt(0)" ::: "memory");

    const char* kg = (const char*)(Kt + bnD + (size_t)(kc * KCH_) * D_) + h * 64;
    const char* vg = (const char*)(VT + (size_t)(bh * DH_) * N_ + kc * KCH_);

    f32x16 of, lacc;
#pragma unroll
    for (int i = 0; i < 16; ++i) { of[i] = 0.f; lacc[i] = 0.f; }
    const f32x16 zero16 = of;
    bf16 onev = (bf16)1.0f;
    bf16x8 ones = {onev, onev, onev, onev, onev, onev, onev, onev};
    int mrow = wid * 32 + ql;

#define STAGE(bufi, it) do {                                                   \
        int k0s = (it) * 64;                                                   \
        gload16(kg + (size_t)(k0s + lane) * 256 + wid * 16,                    \
                kbuf[bufi] + wid * 1024);                                      \
        gload16(vg + ((size_t)(lane & 31) * N_ + k0s) * 2 +                    \
                    (2 * wid + (lane >> 5)) * 16,                              \
                vbuf[bufi] + wid * 1024);                                      \
    } while (0)

    STAGE(0, 0);
    STAGE(1, 1);
    __builtin_amdgcn_s_barrier();   // mask tile visible to all waves

    unsigned long long mcur = *(const unsigned long long*)(&mbuf[mrow][0]);

#pragma unroll 1
    for (int it = 0; it < NIT_; ++it) {
        int cur = it % 3;
        const char* kb_ = kbuf[cur];
        const char* vb_ = vbuf[cur];
        if (it < NIT_ - 1) asm volatile("s_waitcnt vmcnt(2)" ::: "memory");
        else               asm volatile("s_waitcnt vmcnt(0)" ::: "memory");
        __builtin_amdgcn_s_barrier();
        __builtin_amdgcn_sched_barrier(0);
        if (it + 2 < NIT_) STAGE((it + 2) % 3, it + 2);

        unsigned long long mnext = (it + 1 < NIT_)
            ? *(const unsigned long long*)(&mbuf[mrow][(it + 1) * 2]) : 0ull;
        unsigned mw0 = (unsigned)mcur, mw1 = (unsigned)(mcur >> 32);

#pragma unroll
        for (int kb = 0; kb < 2; ++kb) {
            bf16x8 kf0 = *(const bf16x8*)(kb_ + hf * 1024 + (kb * 32 + ql) * 16);
            bf16x8 kf1 = *(const bf16x8*)(kb_ + 2048 + hf * 1024 + (kb * 32 + ql) * 16);
            f32x16 s = mfma32(kf0, qf0, zero16);
            s = mfma32(kf1, qf1, s);

            union { unsigned u[4]; bf16x8 v; } f0, f1;
            if (VAR == 0) {
                unsigned wsh = (kb ? mw1 : mw0) >> (hf * 4);
                float p[16];
#pragma unroll
                for (int r = 0; r < 16; ++r) {
                    int bitp = (r & 3) + 8 * (r >> 2);
                    float e = __builtin_amdgcn_exp2f(s[r]);
                    p[r] = ((wsh >> bitp) & 1u) ? e : 0.f;
                }
                unsigned lo0 = cvtpk(p[0], p[1]),   hi0 = cvtpk(p[2], p[3]);
                unsigned lo1 = cvtpk(p[4], p[5]),   hi1 = cvtpk(p[6], p[7]);
                unsigned lo2 = cvtpk(p[8], p[9]),   hi2 = cvtpk(p[10], p[11]);
                unsigned lo3 = cvtpk(p[12], p[13]), hi3 = cvtpk(p[14], p[15]);
                swap32(lo0, lo1); swap32(hi0, hi1);
                swap32(lo2, lo3); swap32(hi2, hi3);
                f0.u[0] = lo0; f0.u[1] = hi0; f0.u[2] = lo1; f0.u[3] = hi1;
                f1.u[0] = lo2; f1.u[1] = hi2; f1.u[2] = lo3; f1.u[3] = hi3;
            } else {
                // keep QK^T live without any softmax VALU; feed live regs as P
                asm volatile("" :: "v"(s[0]), "v"(s[15]));
                f0.v = qf0;
                f1.v = qf1;
            }

            bf16x8 va = *(const bf16x8*)(vb_ + ((kb * 2 + 0) * 2 + hf) * 512 + ql * 16);
            bf16x8 vb2 = *(const bf16x8*)(vb_ + ((kb * 2 + 1) * 2 + hf) * 512 + ql * 16);
            __builtin_amdgcn_s_setprio(1);
            of = mfma32(va, f0.v, of);
            of = mfma32(vb2, f1.v, of);
            lacc = mfma32(ones, f0.v, lacc);
            lacc = mfma32(ones, f1.v, lacc);
            __builtin_amdgcn_s_setprio(0);
        }
        mcur = mnext;
    }
#undef STAGE

    size_t pb = ((size_t)(kc * 16 + bh) * N_ + qg) * 32;
#pragma unroll
    for (int g = 0; g < 4; ++g) {
        union { unsigned u[2]; bf16x4 v; } pk;
        pk.u[0] = cvtpk(of[4 * g + 0], of[4 * g + 1]);
        pk.u[1] = cvtpk(of[4 * g + 2], of[4 * g + 3]);
        *(bf16x4*)(partO + pb + 8 * g + 4 * hf) = pk.v;
    }
    if (lane < 32)
        partML[(size_t)(kc * 16 + bh) * N_ + qg] = lacc[0];   // all rows equal
}

// ---------------- fused FFN (+ next-step QKV, or final outputs) -------------
template <bool LAST>
__global__ __launch_bounds__(512) void k_ffn(
        const bf16* __restrict__ partO, const float* __restrict__ partML,
        const bf16* __restrict__ woT, const float* __restrict__ bo,
        const bf16* __restrict__ l1T, const float* __restrict__ l1b,
        const float* __restrict__ pra,
        const bf16* __restrict__ l2T, const float* __restrict__ l2b,
        const float* __restrict__ lng, const float* __restrict__ lnb,
        const bf16* __restrict__ wqkvT2, const float* __restrict__ bqkv2,
        const int* __restrict__ entl, float* __restrict__ gout,
        bf16* __restrict__ Qout, bf16* __restrict__ Kout,
        bf16* __restrict__ VTout) {
    __shared__ __align__(16) char Obuf[16 * 256];    // [16][128] bf16 swz
    __shared__ __align__(16) char Tbuf[16 * 256];    // [16][128] bf16 swz
    __shared__ __align__(16) char Hbuf[16 * 1024];   // [16][512] bf16 swz
    __shared__ float lst[8][16][2];
    int t = threadIdx.x;
    int lane = t & 63, wid = t >> 6;
    int lr = lane & 15, lg = lane >> 4;
    int m0 = blockIdx.x * 16;

    // phase 0: combine split-k attention partials -> Obuf (bf16)
    {
        int i = t >> 5, u = t & 31;          // row i, unit u (h*8 + dh4)
        int r = m0 + i, b = r >> 11, q = r & (N_ - 1);
        int h = u >> 3, dh4 = u & 7;
        int bh = b * 4 + h;
        float L = 0.f;
        f32x4 o = {0.f, 0.f, 0.f, 0.f};
#pragma unroll
        for (int kc = 0; kc < SK_; ++kc) {
            size_t base = (size_t)(kc * 16 + bh) * N_ + q;
            L += partML[base];
            bf16x4 pv = *(const bf16x4*)(partO + base * 32 + dh4 * 4);
#pragma unroll
            for (int j = 0; j < 4; ++j) o[j] += (float)pv[j];
        }
        float rL = 1.f / L;
        bf16x4 pk;
#pragma unroll
        for (int j = 0; j < 4; ++j) pk[j] = (bf16)(o[j] * rL);
        *(bf16x4*)(Obuf + i * 256 + ((u * 8) ^ ((i & 7) << 4))) = pk;
    }
    __syncthreads();

    // phase 1: t = LN(Obuf @ woT + bo) -> Tbuf ; wave wid owns cols wid*16..+16
    float tvx[4];
    {
        f32x4 acc = {0.f, 0.f, 0.f, 0.f};
#pragma unroll
        for (int k0 = 0; k0 < 128; k0 += 32) {
            bf16x8 a = *(const bf16x8*)(Obuf + lr * 256 + (((k0 + lg * 8) * 2) ^ ((lr & 7) << 4)));
            bf16x8 bb = *(const bf16x8*)(woT + ((size_t)(wid * 4 + (k0 >> 5)) * 64 + lane) * 8);
            acc = mfma16(a, bb, acc);
        }
        int col = wid * 16 + lr;
        float bs = bo[col];
#pragma unroll
        for (int r2 = 0; r2 < 4; ++r2) tvx[r2] = acc[r2] + bs;
#pragma unroll
        for (int r2 = 0; r2 < 4; ++r2) {
            float sv = tvx[r2], qv = tvx[r2] * tvx[r2];
#pragma unroll
            for (int msk = 1; msk < 16; msk <<= 1) {
                sv += __shfl_xor(sv, msk, 64);
                qv += __shfl_xor(qv, msk, 64);
            }
            if (lr == 0) { lst[wid][lg * 4 + r2][0] = sv; lst[wid][lg * 4 + r2][1] = qv; }
        }
        __syncthreads();
#pragma unroll
        for (int r2 = 0; r2 < 4; ++r2) {
            int row = lg * 4 + r2;
            float S = 0.f, Q2 = 0.f;
#pragma unroll
            for (int w2 = 0; w2 < 8; ++w2) { S += lst[w2][row][0]; Q2 += lst[w2][row][1]; }
            float mean = S * (1.f / 128.f);
            float var = Q2 * (1.f / 128.f) - mean * mean;
            float rstd = rsqrtf(var + 1e-5f);
            float o = (tvx[r2] - mean) * rstd * lng[col] + lnb[col];
            tvx[r2] = o;
            *(bf16*)(Tbuf + row * 256 + ((col * 2) ^ ((row & 7) << 4))) = (bf16)o;
        }
    }
    __syncthreads();

    // phase 2: h = PReLU(Tbuf @ l1T + l1b) -> Hbuf ; wave owns cols wid*64..+64
    {
        f32x4 acc[4];
#pragma unroll
        for (int ni = 0; ni < 4; ++ni) acc[ni] = f32x4{0.f, 0.f, 0.f, 0.f};
#pragma unroll
        for (int k0 = 0; k0 < 128; k0 += 32) {
            bf16x8 a = *(const bf16x8*)(Tbuf + lr * 256 + (((k0 + lg * 8) * 2) ^ ((lr & 7) << 4)));
#pragma unroll
            for (int ni = 0; ni < 4; ++ni) {
                bf16x8 bb = *(const bf16x8*)(l1T + ((size_t)((wid * 4 + ni) * 4 + (k0 >> 5)) * 64 + lane) * 8);
                acc[ni] = mfma16(a, bb, acc[ni]);
            }
        }
#pragma unroll
        for (int ni = 0; ni < 4; ++ni) {
            int col = wid * 64 + ni * 16 + lr;
            float bs = l1b[col], sl = pra[col];
#pragma unroll
            for (int r2 = 0; r2 < 4; ++r2) {
                int row = lg * 4 + r2;
                float v = acc[ni][r2] + bs;
                v = v >= 0.f ? v : sl * v;
                *(bf16*)(Hbuf + row * 1024 + ((col * 2) ^ ((row & 7) << 4))) = (bf16)v;
            }
        }
    }
    __syncthreads();

    // phase 3: out = LN(Hbuf @ l2T + l2b + t) ; wave owns cols wid*16..+16
    {
        f32x4 acc = {0.f, 0.f, 0.f, 0.f};
#pragma unroll
        for (int k0 = 0; k0 < 512; k0 += 32) {
            bf16x8 a = *(const bf16x8*)(Hbuf + lr * 1024 + (((k0 + lg * 8) * 2) ^ ((lr & 7) << 4)));
            bf16x8 bb = *(const bf16x8*)(l2T + ((size_t)(wid * 16 + (k0 >> 5)) * 64 + lane) * 8);
            acc = mfma16(a, bb, acc);
        }
        int col = wid * 16 + lr;
        float bs = l2b[col];
        float vx[4];
#pragma unroll
        for (int r2 = 0; r2 < 4; ++r2)
            vx[r2] = acc[r2] + bs + tvx[r2];   // resid = f32 t (lane-local)
        __syncthreads();   // lst reuse barrier
#pragma unroll
        for (int r2 = 0; r2 < 4; ++r2) {
            float sv = vx[r2], qv = vx[r2] * vx[r2];
#pragma unroll
            for (int msk = 1; msk < 16; msk <<= 1) {
                sv += __shfl_xor(sv, msk, 64);
                qv += __shfl_xor(qv, msk, 64);
            }
            if (lr == 0) { lst[wid][lg * 4 + r2][0] = sv; lst[wid][lg * 4 + r2][1] = qv; }
        }
        __syncthreads();
#pragma unroll
        for (int r2 = 0; r2 < 4; ++r2) {
            int row = lg * 4 + r2;
            float S = 0.f, Q2 = 0.f;
#pragma unroll
            for (int w2 = 0; w2 < 8; ++w2) { S += lst[w2][row][0]; Q2 += lst[w2][row][1]; }
            float mean = S * (1.f / 128.f);
            float var = Q2 * (1.f / 128.f) - mean * mean;
            float rstd = rsqrtf(var + 1e-5f);
            float o = (vx[r2] - mean) * rstd * lng[col] + lnb[col];
            size_t rowg = (size_t)(m0 + row);
            if (LAST) {
                float* gents = gout + 512;
                gents[rowg * 128 + col] = o;
                int b = (int)(rowg >> 11);
                if ((int)(rowg & (N_ - 1)) == entl[b])
                    gout[b * 128 + col] = o;          // glob
            } else {
                *(bf16*)(Obuf + row * 256 + ((col * 2) ^ ((row & 7) << 4))) = (bf16)o;
            }
        }
        if (LAST && t < 16)
            gout[512 + (size_t)M_ * 128 + m0 + t] = 1.0f;   // emask
    }

    // phase 4 (!LAST): QKV projection of the 16 fresh rows for next prop step
    if (!LAST) {
        __syncthreads();
        f32x4 acc[3];
#pragma unroll
        for (int ni = 0; ni < 3; ++ni) acc[ni] = f32x4{0.f, 0.f, 0.f, 0.f};
#pragma unroll
        for (int k0 = 0; k0 < 128; k0 += 32) {
            bf16x8 a = *(const bf16x8*)(Obuf + lr * 256 + (((k0 + lg * 8) * 2) ^ ((lr & 7) << 4)));
#pragma unroll
            for (int ni = 0; ni < 3; ++ni) {
                bf16x8 bb = *(const bf16x8*)(wqkvT2 + ((size_t)((wid * 3 + ni) * 4 + (k0 >> 5)) * 64 + lane) * 8);
                acc[ni] = mfma16(a, bb, acc[ni]);
            }
        }
#pragma unroll
        for (int ni = 0; ni < 3; ++ni) {
            int col = wid * 48 + ni * 16 + lr;
            float bs = bqkv2[col];
            int rowb = m0 + lg * 4;
            if (col < 128) {
#pragma unroll
                for (int r = 0; r < 4; ++r)
                    Qout[(size_t)(rowb + r) * D_ + col] = (bf16)(acc[ni][r] + bs);
            } else if (col < 256) {
#pragma unroll
                for (int r = 0; r < 4; ++r)
                    Kout[(size_t)(rowb + r) * D_ + (col - 128)] = (bf16)(acc[ni][r] + bs);
            } else {
                int d = col - 256, h = d >> 5, dh = d & 31;
                int b = rowb >> 11, nn = rowb & (N_ - 1);
                bf16x4 pk;
#pragma unroll
                for (int r = 0; r < 4; ++r) pk[r] = (bf16)(acc[ni][r] + bs);
                *(bf16x4*)(VTout + ((size_t)(b * H_ + h) * DH_ + dh) * N_ + nn) = pk;
            }
        }
    }
}

extern "C" void kernel_launch(void* const* d_in, const int* in_sizes, int n_in,
                              void* d_out, int out_size, void* d_ws, size_t ws_size,
                              hipStream_t stream) {
    const float* vents = (const float*)d_in[0];
    const int*   rels  = (const int*)d_in[1];
    const int*   adj   = (const int*)d_in[2];
    const int*   entl  = (const int*)d_in[3];
    const float* renc  = (const float*)d_in[4];
    const float* Wq = (const float*)d_in[5];
    const float* bq = (const float*)d_in[6];
    const float* Wk = (const float*)d_in[7];
    const float* bk = (const float*)d_in[8];
    const float* Wv = (const float*)d_in[9];
    const float* bv = (const float*)d_in[10];
    const float* Wo = (const float*)d_in[11];
    const float* bo = (const float*)d_in[12];
    const float* l1w = (const float*)d_in[13];
    const float* l1b = (const float*)d_in[14];
    const float* l2w = (const float*)d_in[15];
    const float* l2b = (const float*)d_in[16];
    const float* lng = (const float*)d_in[17];
    const float* lnb = (const float*)d_in[18];
    const float* pra = (const float*)d_in[19];

    char* w = (char*)d_ws;
    auto alloc = [&](size_t bytes) { char* r = w; w += (bytes + 255) & ~(size_t)255; return r; };
    unsigned int* mw = (unsigned int*)alloc((size_t)B_ * N_ * NW_ * 4);
    bf16*  wqkvT = (bf16*)alloc((size_t)P_ * 384 * 128 * 2);
    float* bqkv  = (float*)alloc((size_t)P_ * 384 * 4);
    bf16*  woT   = (bf16*)alloc((size_t)P_ * 128 * 128 * 2);
    bf16*  l1T   = (bf16*)alloc((size_t)P_ * 512 * 128 * 2);
    bf16*  l2T   = (bf16*)alloc((size_t)P_ * 128 * 512 * 2);
    bf16*  Qb    = (bf16*)alloc((size_t)M_ * D_ * 2);
    bf16*  Kb    = (bf16*)alloc((size_t)M_ * D_ * 2);
    bf16*  VTb   = (bf16*)alloc((size_t)M_ * D_ * 2);
    bf16*  partO  = (bf16*)alloc((size_t)SK_ * 16 * N_ * 32 * 2);    // 8 MiB
    float* partML = (float*)alloc((size_t)SK_ * 16 * N_ * 4);        // 0.5 MiB
    float* gout  = (float*)d_out;

    const int PRB = QKVB_ + (MKN_ + PRN_ + 255) / 256;
    k_prep<<<PRB, 256, 0, stream>>>(
        vents, rels, renc, adj, Wq, Wk, Wv, Wo, l1w, l2w, bq, bk, bv,
        mw, wqkvT, bqkv, woT, l1T, l2T, Qb, Kb, VTb);
    // ===== MEASUREMENT: one softmax-stub attn launch (garbage output,   =====
    // ===== fully overwritten by the real launch). T(stub) = total-107.4 =====
    k_attn<1><<<dim3(16, 16, SK_), 256, 0, stream>>>(Qb, Kb, VTb, mw, partO, partML);
    // step 0
    k_attn<0><<<dim3(16, 16, SK_), 256, 0, stream>>>(Qb, Kb, VTb, mw, partO, partML);
    k_ffn<false><<<M_ / 16, 512, 0, stream>>>(
        partO, partML, woT, bo, l1T, l1b, pra, l2T, l2b, lng, lnb,
        wqkvT + (size_t)384 * 128, bqkv + 384, entl, nullptr, Qb, Kb, VTb);
    // step 1
    k_attn<0><<<dim3(16, 16, SK_), 256, 0, stream>>>(Qb, Kb, VTb, mw, partO, partML);
    k_ffn<true><<<M_ / 16, 512, 0, stream>>>(
        partO, partML, woT + (size_t)16384, bo + 128,
        l1T + (size_t)65536, l1b + 512, pra + 512,
        l2T + (size_t)65536, l2b + 128, lng + 128, lnb + 128,
        wqkvT, bqkv, entl, gout, Qb, Kb, VTb);
}

// Round 19
// 109.285 us; speedup vs baseline: 1.1309x; 1.1309x over previous
//
#include <hip/hip_runtime.h>
#include <hip/hip_bf16.h>

typedef __bf16 bf16;
typedef __bf16 bf16x4 __attribute__((ext_vector_type(4)));
typedef __bf16 bf16x8 __attribute__((ext_vector_type(8)));
typedef float f32x4 __attribute__((ext_vector_type(4)));
typedef float f32x16 __attribute__((ext_vector_type(16)));

#define B_ 4
#define NE_ 1536
#define NR_ 512
#define N_ 2048
#define D_ 128
#define H_ 4
#define DH_ 32
#define P_ 2
#define M_ (B_*N_)      // 8192 rows total
#define NW_ (N_/32)     // 64 mask words per row
#define SK_ 4           // split-k chunks for attention
#define KCH_ (N_/SK_)   // 512 k per chunk
#define NIT_ (KCH_/64)  // 8 kv-tiles of 64 per chunk

__device__ __forceinline__ f32x4 mfma16(bf16x8 a, bf16x8 b, f32x4 c) {
    return __builtin_amdgcn_mfma_f32_16x16x32_bf16(a, b, c, 0, 0, 0);
}
__device__ __forceinline__ f32x16 mfma32(bf16x8 a, bf16x8 b, f32x16 c) {
    return __builtin_amdgcn_mfma_f32_32x32x16_bf16(a, b, c, 0, 0, 0);
}
__device__ __forceinline__ unsigned cvtpk(float lo, float hi) {
    unsigned r;
    asm("v_cvt_pk_bf16_f32 %0, %1, %2" : "=v"(r) : "v"(lo), "v"(hi));
    return r;
}
__device__ __forceinline__ void swap32(unsigned& a, unsigned& b) {
    asm("v_permlane32_swap_b32 %0, %1" : "+v"(a), "+v"(b));
}
__device__ __forceinline__ void gload16(const void* g, void* l) {
    __builtin_amdgcn_global_load_lds(
        (const __attribute__((address_space(1))) void*)g,
        (__attribute__((address_space(3))) void*)l, 16, 0, 0);
}

// fragment-major weight index: col c (out), k i, depth K.
__device__ __forceinline__ size_t fragidx(int c, int i, int K) {
    int nb = c >> 4, kc = i >> 5;
    int l = ((i >> 3) & 3) * 16 + (c & 15);
    return ((size_t)(nb * (K >> 5) + kc) * 64 + l) * 8 + (i & 7);
}

// ---------------- merged prep: QKV-p0 (direct f32) + mask-pack + repack -----
#define QKVB_ 768                // 128 m-tiles x 6 n-tiles
#define MKN_ (B_*N_*NW_)         // 524288 mask words
#define PPER_ (3*16384 + 16384 + 65536 + 65536 + 384)   // 196992
#define PRN_ (P_*PPER_)          // 393984
__global__ __launch_bounds__(256) void k_prep(
        const float* __restrict__ vents, const int* __restrict__ rels,
        const float* __restrict__ renc, const int* __restrict__ adj,
        const float* __restrict__ Wq, const float* __restrict__ Wk,
        const float* __restrict__ Wv, const float* __restrict__ Wo,
        const float* __restrict__ l1w, const float* __restrict__ l2w,
        const float* __restrict__ bq, const float* __restrict__ bk,
        const float* __restrict__ bv,
        unsigned int* __restrict__ mw,
        bf16* __restrict__ wqkvT, float* __restrict__ bqkv,
        bf16* __restrict__ woT, bf16* __restrict__ l1T,
        bf16* __restrict__ l2T,
        bf16* __restrict__ Qout, bf16* __restrict__ Kout,
        bf16* __restrict__ VTout) {
    const float SC = 0.25503330560513437f;     // (1/sqrt(32)) * log2(e)
    if (blockIdx.x < QKVB_) {
        int qb = blockIdx.x;
        int mt = qb / 6, nt = qb % 6;
        int lane = threadIdx.x & 63, wid = threadIdx.x >> 6;
        int wr = wid >> 1, wc = wid & 1;
        int m0 = mt * 64 + wr * 32;
        int n0 = nt * 64 + wc * 32;
        int lr = lane & 15, lg = lane >> 4;
        const float* srcA[2];
#pragma unroll
        for (int mi = 0; mi < 2; ++mi) {
            int row = m0 + mi * 16 + lr;
            int n = row & (N_ - 1), b = row >> 11;
            srcA[mi] = (n < NE_) ? vents + ((size_t)(b * NE_ + n)) * D_
                                 : renc + (size_t)rels[b * NR_ + (n - NE_)] * D_;
        }
        f32x4 acc[2][2];
#pragma unroll
        for (int mi = 0; mi < 2; ++mi)
#pragma unroll
            for (int ni = 0; ni < 2; ++ni)
                acc[mi][ni] = f32x4{0.f, 0.f, 0.f, 0.f};
        for (int k0 = 0; k0 < 128; k0 += 32) {
            bf16x8 a[2], bb[2];
#pragma unroll
            for (int mi = 0; mi < 2; ++mi) {
                float4 f0 = *(const float4*)(srcA[mi] + k0 + lg * 8);
                float4 f1 = *(const float4*)(srcA[mi] + k0 + lg * 8 + 4);
                bf16x8 v;
                v[0] = (bf16)f0.x; v[1] = (bf16)f0.y; v[2] = (bf16)f0.z; v[3] = (bf16)f0.w;
                v[4] = (bf16)f1.x; v[5] = (bf16)f1.y; v[6] = (bf16)f1.z; v[7] = (bf16)f1.w;
                a[mi] = v;
            }
#pragma unroll
            for (int ni = 0; ni < 2; ++ni) {
                int col = n0 + ni * 16 + lr;
                int which = col >> 7, c0 = col & 127;
                const float* W = which == 0 ? Wq : (which == 1 ? Wk : Wv);
                float sc = which == 0 ? SC : 1.f;
                bf16x8 v;
#pragma unroll
                for (int e = 0; e < 8; ++e)
                    v[e] = (bf16)(W[(size_t)(k0 + lg * 8 + e) * 128 + c0] * sc);
                bb[ni] = v;
            }
#pragma unroll
            for (int mi = 0; mi < 2; ++mi)
#pragma unroll
                for (int ni = 0; ni < 2; ++ni)
                    acc[mi][ni] = mfma16(a[mi], bb[ni], acc[mi][ni]);
        }
#pragma unroll
        for (int mi = 0; mi < 2; ++mi) {
#pragma unroll
            for (int ni = 0; ni < 2; ++ni) {
                int col = n0 + ni * 16 + lr;
                int which = col >> 7, c0 = col & 127;
                float bs = which == 0 ? bq[c0] * SC : (which == 1 ? bk[c0] : bv[c0]);
                int rowb = m0 + mi * 16 + lg * 4;
                if (which == 0) {
#pragma unroll
                    for (int r = 0; r < 4; ++r)
                        Qout[(size_t)(rowb + r) * D_ + c0] = (bf16)(acc[mi][ni][r] + bs);
                } else if (which == 1) {
#pragma unroll
                    for (int r = 0; r < 4; ++r)
                        Kout[(size_t)(rowb + r) * D_ + c0] = (bf16)(acc[mi][ni][r] + bs);
                } else {
                    int h = c0 >> 5, dh = c0 & 31;
                    int b = rowb >> 11, nn = rowb & (N_ - 1);
                    bf16x4 pk;
#pragma unroll
                    for (int r = 0; r < 4; ++r) pk[r] = (bf16)(acc[mi][ni][r] + bs);
                    *(bf16x4*)(VTout + ((size_t)(b * H_ + h) * DH_ + dh) * N_ + nn) = pk;
                }
            }
        }
        return;
    }
    int idx = (blockIdx.x - QKVB_) * 256 + threadIdx.x;
    if (idx < MKN_) {
        const int4* a = (const int4*)(adj + (size_t)idx * 32);
        unsigned int w = 0;
#pragma unroll
        for (int q = 0; q < 8; ++q) {
            int4 t = a[q];
            w |= (t.x != 0 ? 1u : 0u) << (q * 4 + 0);
            w |= (t.y != 0 ? 1u : 0u) << (q * 4 + 1);
            w |= (t.z != 0 ? 1u : 0u) << (q * 4 + 2);
            w |= (t.w != 0 ? 1u : 0u) << (q * 4 + 3);
        }
        mw[idx] = w;
        return;
    }
    idx -= MKN_;
    if (idx >= PRN_) return;
    int p = idx / PPER_;
    int r = idx % PPER_;
    if (r < 3 * 16384) {
        int which = r / 16384, e = r % 16384;
        int o = e >> 7, i = e & 127;
        const float* W = which == 0 ? Wq : (which == 1 ? Wk : Wv);
        float v = W[(size_t)(p * 128 + i) * 128 + o];
        if (which == 0) v *= SC;
        wqkvT[(size_t)p * 384 * 128 + fragidx(which * 128 + o, i, 128)] = (bf16)v;
    } else if ((r -= 3 * 16384) < 16384) {
        int o = r >> 7, i = r & 127;
        woT[(size_t)p * 16384 + fragidx(o, i, 128)] = (bf16)Wo[(size_t)(p * 128 + i) * 128 + o];
    } else if ((r -= 16384) < 65536) {
        int o = r >> 7, i = r & 127;          // o<512, i<128
        l1T[(size_t)p * 65536 + fragidx(o, i, 128)] = (bf16)l1w[(size_t)(p * 128 + i) * 512 + o];
    } else if ((r -= 65536) < 65536) {
        int o = r >> 9, i = r & 511;          // o<128, i<512
        l2T[(size_t)p * 65536 + fragidx(o, i, 512)] = (bf16)l2w[(size_t)(p * 512 + i) * 128 + o];
    } else {
        r -= 65536;
        float v = r < 128 ? bq[p * 128 + r] * SC
                          : (r < 256 ? bk[p * 128 + r - 128] : bv[p * 128 + r - 256]);
        bqkv[p * 384 + r] = v;
    }
}

// ---------------- fused flash attention: both-S-first chain-break -----------
// grid (16, 16, SK), block 256 (4 waves); wave: 32 q-rows, 64 k per iter.
// Both kb sub-blocks' S-MFMAs are issued up-front so softmax(kb1) VALU can
// overlap PV(kb0) MFMA issue/latency (previously S1 came after PV0, blocking
// any overlap). Ring-3 LDS, counted vmcnt, ones-MFMA lsum.
__global__ __launch_bounds__(256) void k_attn(
    const bf16* __restrict__ Q, const bf16* __restrict__ Kt,
    const bf16* __restrict__ VT, const unsigned int* __restrict__ mw,
    bf16* __restrict__ partO, float* __restrict__ partML) {
    __shared__ __align__(16) char kbuf[3][4096];   // [slot: m*2+hf][64 k][16B]
    __shared__ __align__(16) char vbuf[3][4096];   // [slot: kt'*2+hf][32 dh][16B]
    __shared__ __align__(16) unsigned mbuf[128][18];   // 9KB mask tile, padded
    int wid = threadIdx.x >> 6;
    int lane = threadIdx.x & 63;
    int ql = lane & 31, hf = lane >> 5;
    int qx = blockIdx.x;
    int bh = blockIdx.y;
    int kc = blockIdx.z;
    int b = bh >> 2, h = bh & 3;
    int qg = qx * 128 + wid * 32 + ql;
    const size_t bnD = (size_t)b * N_ * D_;

    const bf16* qp = Q + bnD + (size_t)qg * D_ + h * 32 + hf * 8;
    bf16x8 qf0 = *(const bf16x8*)(qp);
    bf16x8 qf1 = *(const bf16x8*)(qp + 16);

    // stage this block's 128 q-rows x 16 mask words into LDS
#pragma unroll
    for (int j = 0; j < 2; ++j) {
        int u = threadIdx.x + 256 * j;               // 0..511
        int row = u >> 2, sub = u & 3;
        uint4 mv = *(const uint4*)(mw + ((size_t)b * N_ + qx * 128 + row) * NW_
                                      + kc * (KCH_ / 32) + sub * 4);
        uint2 lo; lo.x = mv.x; lo.y = mv.y;
        uint2 hi; hi.x = mv.z; hi.y = mv.w;
        *(uint2*)(&mbuf[row][sub * 4]) = lo;
        *(uint2*)(&mbuf[row][sub * 4 + 2]) = hi;
    }
    asm volatile("s_waitcnt lgkmcnt(0)" ::: "memory");

    const char* kg = (const char*)(Kt + bnD + (size_t)(kc * KCH_) * D_) + h * 64;
    const char* vg = (const char*)(VT + (size_t)(bh * DH_) * N_ + kc * KCH_);

    f32x16 of, lacc;
#pragma unroll
    for (int i = 0; i < 16; ++i) { of[i] = 0.f; lacc[i] = 0.f; }
    const f32x16 zero16 = of;
    bf16 onev = (bf16)1.0f;
    bf16x8 ones = {onev, onev, onev, onev, onev, onev, onev, onev};
    int mrow = wid * 32 + ql;

#define STAGE(bufi, it) do {                                                   \
        int k0s = (it) * 64;                                                   \
        gload16(kg + (size_t)(k0s + lane) * 256 + wid * 16,                    \
                kbuf[bufi] + wid * 1024);                                      \
        gload16(vg + ((size_t)(lane & 31) * N_ + k0s) * 2 +                    \
                    (2 * wid + (lane >> 5)) * 16,                              \
                vbuf[bufi] + wid * 1024);                                      \
    } while (0)

    STAGE(0, 0);
    STAGE(1, 1);
    __builtin_amdgcn_s_barrier();   // mask tile visible to all waves

    unsigned long long mcur = *(const unsigned long long*)(&mbuf[mrow][0]);

#pragma unroll 1
    for (int it = 0; it < NIT_; ++it) {
        int cur = it % 3;
        const char* kb_ = kbuf[cur];
        const char* vb_ = vbuf[cur];
        if (it < NIT_ - 1) asm volatile("s_waitcnt vmcnt(2)" ::: "memory");
        else               asm volatile("s_waitcnt vmcnt(0)" ::: "memory");
        __builtin_amdgcn_s_barrier();
        __builtin_amdgcn_sched_barrier(0);
        if (it + 2 < NIT_) STAGE((it + 2) % 3, it + 2);

        unsigned long long mnext = (it + 1 < NIT_)
            ? *(const unsigned long long*)(&mbuf[mrow][(it + 1) * 2]) : 0ull;
        unsigned mwv[2];
        mwv[0] = (unsigned)mcur; mwv[1] = (unsigned)(mcur >> 32);

        // ---- both S blocks first (frees softmax(kb1) to overlap PV(kb0)) ----
        f32x16 s[2];
#pragma unroll
        for (int kb = 0; kb < 2; ++kb) {
            bf16x8 kf0 = *(const bf16x8*)(kb_ + hf * 1024 + (kb * 32 + ql) * 16);
            bf16x8 kf1 = *(const bf16x8*)(kb_ + 2048 + hf * 1024 + (kb * 32 + ql) * 16);
            s[kb] = mfma32(kf0, qf0, zero16);
            s[kb] = mfma32(kf1, qf1, s[kb]);
        }

#pragma unroll
        for (int kb = 0; kb < 2; ++kb) {
            unsigned wsh = mwv[kb] >> (hf * 4);
            float p[16];
#pragma unroll
            for (int r = 0; r < 16; ++r) {
                int bitp = (r & 3) + 8 * (r >> 2);
                float e = __builtin_amdgcn_exp2f(s[kb][r]);
                p[r] = ((wsh >> bitp) & 1u) ? e : 0.f;
            }
            unsigned lo0 = cvtpk(p[0], p[1]),   hi0 = cvtpk(p[2], p[3]);
            unsigned lo1 = cvtpk(p[4], p[5]),   hi1 = cvtpk(p[6], p[7]);
            unsigned lo2 = cvtpk(p[8], p[9]),   hi2 = cvtpk(p[10], p[11]);
            unsigned lo3 = cvtpk(p[12], p[13]), hi3 = cvtpk(p[14], p[15]);
            swap32(lo0, lo1); swap32(hi0, hi1);
            swap32(lo2, lo3); swap32(hi2, hi3);
            union { unsigned u[4]; bf16x8 v; } f0, f1;
            f0.u[0] = lo0; f0.u[1] = hi0; f0.u[2] = lo1; f0.u[3] = hi1;
            f1.u[0] = lo2; f1.u[1] = hi2; f1.u[2] = lo3; f1.u[3] = hi3;

            bf16x8 va = *(const bf16x8*)(vb_ + ((kb * 2 + 0) * 2 + hf) * 512 + ql * 16);
            bf16x8 vb2 = *(const bf16x8*)(vb_ + ((kb * 2 + 1) * 2 + hf) * 512 + ql * 16);
            __builtin_amdgcn_s_setprio(1);
            of = mfma32(va, f0.v, of);
            of = mfma32(vb2, f1.v, of);
            lacc = mfma32(ones, f0.v, lacc);
            lacc = mfma32(ones, f1.v, lacc);
            __builtin_amdgcn_s_setprio(0);
        }
        mcur = mnext;
    }
#undef STAGE

    size_t pb = ((size_t)(kc * 16 + bh) * N_ + qg) * 32;
#pragma unroll
    for (int g = 0; g < 4; ++g) {
        union { unsigned u[2]; bf16x4 v; } pk;
        pk.u[0] = cvtpk(of[4 * g + 0], of[4 * g + 1]);
        pk.u[1] = cvtpk(of[4 * g + 2], of[4 * g + 3]);
        *(bf16x4*)(partO + pb + 8 * g + 4 * hf) = pk.v;
    }
    if (lane < 32)
        partML[(size_t)(kc * 16 + bh) * N_ + qg] = lacc[0];   // all rows equal
}

// ---------------- fused FFN (+ next-step QKV, or final outputs) -------------
template <bool LAST>
__global__ __launch_bounds__(512) void k_ffn(
        const bf16* __restrict__ partO, const float* __restrict__ partML,
        const bf16* __restrict__ woT, const float* __restrict__ bo,
        const bf16* __restrict__ l1T, const float* __restrict__ l1b,
        const float* __restrict__ pra,
        const bf16* __restrict__ l2T, const float* __restrict__ l2b,
        const float* __restrict__ lng, const float* __restrict__ lnb,
        const bf16* __restrict__ wqkvT2, const float* __restrict__ bqkv2,
        const int* __restrict__ entl, float* __restrict__ gout,
        bf16* __restrict__ Qout, bf16* __restrict__ Kout,
        bf16* __restrict__ VTout) {
    __shared__ __align__(16) char Obuf[16 * 256];    // [16][128] bf16 swz
    __shared__ __align__(16) char Tbuf[16 * 256];    // [16][128] bf16 swz
    __shared__ __align__(16) char Hbuf[16 * 1024];   // [16][512] bf16 swz
    __shared__ float lst[8][16][2];
    int t = threadIdx.x;
    int lane = t & 63, wid = t >> 6;
    int lr = lane & 15, lg = lane >> 4;
    int m0 = blockIdx.x * 16;

    // phase 0: combine split-k attention partials -> Obuf (bf16)
    {
        int i = t >> 5, u = t & 31;          // row i, unit u (h*8 + dh4)
        int r = m0 + i, b = r >> 11, q = r & (N_ - 1);
        int h = u >> 3, dh4 = u & 7;
        int bh = b * 4 + h;
        float L = 0.f;
        f32x4 o = {0.f, 0.f, 0.f, 0.f};
#pragma unroll
        for (int kc = 0; kc < SK_; ++kc) {
            size_t base = (size_t)(kc * 16 + bh) * N_ + q;
            L += partML[base];
            bf16x4 pv = *(const bf16x4*)(partO + base * 32 + dh4 * 4);
#pragma unroll
            for (int j = 0; j < 4; ++j) o[j] += (float)pv[j];
        }
        float rL = 1.f / L;
        bf16x4 pk;
#pragma unroll
        for (int j = 0; j < 4; ++j) pk[j] = (bf16)(o[j] * rL);
        *(bf16x4*)(Obuf + i * 256 + ((u * 8) ^ ((i & 7) << 4))) = pk;
    }
    __syncthreads();

    // phase 1: t = LN(Obuf @ woT + bo) -> Tbuf ; wave wid owns cols wid*16..+16
    float tvx[4];
    {
        f32x4 acc = {0.f, 0.f, 0.f, 0.f};
#pragma unroll
        for (int k0 = 0; k0 < 128; k0 += 32) {
            bf16x8 a = *(const bf16x8*)(Obuf + lr * 256 + (((k0 + lg * 8) * 2) ^ ((lr & 7) << 4)));
            bf16x8 bb = *(const bf16x8*)(woT + ((size_t)(wid * 4 + (k0 >> 5)) * 64 + lane) * 8);
            acc = mfma16(a, bb, acc);
        }
        int col = wid * 16 + lr;
        float bs = bo[col];
#pragma unroll
        for (int r2 = 0; r2 < 4; ++r2) tvx[r2] = acc[r2] + bs;
#pragma unroll
        for (int r2 = 0; r2 < 4; ++r2) {
            float sv = tvx[r2], qv = tvx[r2] * tvx[r2];
#pragma unroll
            for (int msk = 1; msk < 16; msk <<= 1) {
                sv += __shfl_xor(sv, msk, 64);
                qv += __shfl_xor(qv, msk, 64);
            }
            if (lr == 0) { lst[wid][lg * 4 + r2][0] = sv; lst[wid][lg * 4 + r2][1] = qv; }
        }
        __syncthreads();
#pragma unroll
        for (int r2 = 0; r2 < 4; ++r2) {
            int row = lg * 4 + r2;
            float S = 0.f, Q2 = 0.f;
#pragma unroll
            for (int w2 = 0; w2 < 8; ++w2) { S += lst[w2][row][0]; Q2 += lst[w2][row][1]; }
            float mean = S * (1.f / 128.f);
            float var = Q2 * (1.f / 128.f) - mean * mean;
            float rstd = rsqrtf(var + 1e-5f);
            float o = (tvx[r2] - mean) * rstd * lng[col] + lnb[col];
            tvx[r2] = o;
            *(bf16*)(Tbuf + row * 256 + ((col * 2) ^ ((row & 7) << 4))) = (bf16)o;
        }
    }
    __syncthreads();

    // phase 2: h = PReLU(Tbuf @ l1T + l1b) -> Hbuf ; wave owns cols wid*64..+64
    {
        f32x4 acc[4];
#pragma unroll
        for (int ni = 0; ni < 4; ++ni) acc[ni] = f32x4{0.f, 0.f, 0.f, 0.f};
#pragma unroll
        for (int k0 = 0; k0 < 128; k0 += 32) {
            bf16x8 a = *(const bf16x8*)(Tbuf + lr * 256 + (((k0 + lg * 8) * 2) ^ ((lr & 7) << 4)));
#pragma unroll
            for (int ni = 0; ni < 4; ++ni) {
                bf16x8 bb = *(const bf16x8*)(l1T + ((size_t)((wid * 4 + ni) * 4 + (k0 >> 5)) * 64 + lane) * 8);
                acc[ni] = mfma16(a, bb, acc[ni]);
            }
        }
#pragma unroll
        for (int ni = 0; ni < 4; ++ni) {
            int col = wid * 64 + ni * 16 + lr;
            float bs = l1b[col], sl = pra[col];
#pragma unroll
            for (int r2 = 0; r2 < 4; ++r2) {
                int row = lg * 4 + r2;
                float v = acc[ni][r2] + bs;
                v = v >= 0.f ? v : sl * v;
                *(bf16*)(Hbuf + row * 1024 + ((col * 2) ^ ((row & 7) << 4))) = (bf16)v;
            }
        }
    }
    __syncthreads();

    // phase 3: out = LN(Hbuf @ l2T + l2b + t) ; wave owns cols wid*16..+16
    {
        f32x4 acc = {0.f, 0.f, 0.f, 0.f};
#pragma unroll
        for (int k0 = 0; k0 < 512; k0 += 32) {
            bf16x8 a = *(const bf16x8*)(Hbuf + lr * 1024 + (((k0 + lg * 8) * 2) ^ ((lr & 7) << 4)));
            bf16x8 bb = *(const bf16x8*)(l2T + ((size_t)(wid * 16 + (k0 >> 5)) * 64 + lane) * 8);
            acc = mfma16(a, bb, acc);
        }
        int col = wid * 16 + lr;
        float bs = l2b[col];
        float vx[4];
#pragma unroll
        for (int r2 = 0; r2 < 4; ++r2)
            vx[r2] = acc[r2] + bs + tvx[r2];   // resid = f32 t (lane-local)
        __syncthreads();   // lst reuse barrier
#pragma unroll
        for (int r2 = 0; r2 < 4; ++r2) {
            float sv = vx[r2], qv = vx[r2] * vx[r2];
#pragma unroll
            for (int msk = 1; msk < 16; msk <<= 1) {
                sv += __shfl_xor(sv, msk, 64);
                qv += __shfl_xor(qv, msk, 64);
            }
            if (lr == 0) { lst[wid][lg * 4 + r2][0] = sv; lst[wid][lg * 4 + r2][1] = qv; }
        }
        __syncthreads();
#pragma unroll
        for (int r2 = 0; r2 < 4; ++r2) {
            int row = lg * 4 + r2;
            float S = 0.f, Q2 = 0.f;
#pragma unroll
            for (int w2 = 0; w2 < 8; ++w2) { S += lst[w2][row][0]; Q2 += lst[w2][row][1]; }
            float mean = S * (1.f / 128.f);
            float var = Q2 * (1.f / 128.f) - mean * mean;
            float rstd = rsqrtf(var + 1e-5f);
            float o = (vx[r2] - mean) * rstd * lng[col] + lnb[col];
            size_t rowg = (size_t)(m0 + row);
            if (LAST) {
                float* gents = gout + 512;
                gents[rowg * 128 + col] = o;
                int b = (int)(rowg >> 11);
                if ((int)(rowg & (N_ - 1)) == entl[b])
                    gout[b * 128 + col] = o;          // glob
            } else {
                *(bf16*)(Obuf + row * 256 + ((col * 2) ^ ((row & 7) << 4))) = (bf16)o;
            }
        }
        if (LAST && t < 16)
            gout[512 + (size_t)M_ * 128 + m0 + t] = 1.0f;   // emask
    }

    // phase 4 (!LAST): QKV projection of the 16 fresh rows for next prop step
    if (!LAST) {
        __syncthreads();
        f32x4 acc[3];
#pragma unroll
        for (int ni = 0; ni < 3; ++ni) acc[ni] = f32x4{0.f, 0.f, 0.f, 0.f};
#pragma unroll
        for (int k0 = 0; k0 < 128; k0 += 32) {
            bf16x8 a = *(const bf16x8*)(Obuf + lr * 256 + (((k0 + lg * 8) * 2) ^ ((lr & 7) << 4)));
#pragma unroll
            for (int ni = 0; ni < 3; ++ni) {
                bf16x8 bb = *(const bf16x8*)(wqkvT2 + ((size_t)((wid * 3 + ni) * 4 + (k0 >> 5)) * 64 + lane) * 8);
                acc[ni] = mfma16(a, bb, acc[ni]);
            }
        }
#pragma unroll
        for (int ni = 0; ni < 3; ++ni) {
            int col = wid * 48 + ni * 16 + lr;
            float bs = bqkv2[col];
            int rowb = m0 + lg * 4;
            if (col < 128) {
#pragma unroll
                for (int r = 0; r < 4; ++r)
                    Qout[(size_t)(rowb + r) * D_ + col] = (bf16)(acc[ni][r] + bs);
            } else if (col < 256) {
#pragma unroll
                for (int r = 0; r < 4; ++r)
                    Kout[(size_t)(rowb + r) * D_ + (col - 128)] = (bf16)(acc[ni][r] + bs);
            } else {
                int d = col - 256, h = d >> 5, dh = d & 31;
                int b = rowb >> 11, nn = rowb & (N_ - 1);
                bf16x4 pk;
#pragma unroll
                for (int r = 0; r < 4; ++r) pk[r] = (bf16)(acc[ni][r] + bs);
                *(bf16x4*)(VTout + ((size_t)(b * H_ + h) * DH_ + dh) * N_ + nn) = pk;
            }
        }
    }
}

extern "C" void kernel_launch(void* const* d_in, const int* in_sizes, int n_in,
                              void* d_out, int out_size, void* d_ws, size_t ws_size,
                              hipStream_t stream) {
    const float* vents = (const float*)d_in[0];
    const int*   rels  = (const int*)d_in[1];
    const int*   adj   = (const int*)d_in[2];
    const int*   entl  = (const int*)d_in[3];
    const float* renc  = (const float*)d_in[4];
    const float* Wq = (const float*)d_in[5];
    const float* bq = (const float*)d_in[6];
    const float* Wk = (const float*)d_in[7];
    const float* bk = (const float*)d_in[8];
    const float* Wv = (const float*)d_in[9];
    const float* bv = (const float*)d_in[10];
    const float* Wo = (const float*)d_in[11];
    const float* bo = (const float*)d_in[12];
    const float* l1w = (const float*)d_in[13];
    const float* l1b = (const float*)d_in[14];
    const float* l2w = (const float*)d_in[15];
    const float* l2b = (const float*)d_in[16];
    const float* lng = (const float*)d_in[17];
    const float* lnb = (const float*)d_in[18];
    const float* pra = (const float*)d_in[19];

    char* w = (char*)d_ws;
    auto alloc = [&](size_t bytes) { char* r = w; w += (bytes + 255) & ~(size_t)255; return r; };
    unsigned int* mw = (unsigned int*)alloc((size_t)B_ * N_ * NW_ * 4);
    bf16*  wqkvT = (bf16*)alloc((size_t)P_ * 384 * 128 * 2);
    float* bqkv  = (float*)alloc((size_t)P_ * 384 * 4);
    bf16*  woT   = (bf16*)alloc((size_t)P_ * 128 * 128 * 2);
    bf16*  l1T   = (bf16*)alloc((size_t)P_ * 512 * 128 * 2);
    bf16*  l2T   = (bf16*)alloc((size_t)P_ * 128 * 512 * 2);
    bf16*  Qb    = (bf16*)alloc((size_t)M_ * D_ * 2);
    bf16*  Kb    = (bf16*)alloc((size_t)M_ * D_ * 2);
    bf16*  VTb   = (bf16*)alloc((size_t)M_ * D_ * 2);
    bf16*  partO  = (bf16*)alloc((size_t)SK_ * 16 * N_ * 32 * 2);    // 8 MiB
    float* partML = (float*)alloc((size_t)SK_ * 16 * N_ * 4);        // 0.5 MiB
    float* gout  = (float*)d_out;

    const int PRB = QKVB_ + (MKN_ + PRN_ + 255) / 256;
    k_prep<<<PRB, 256, 0, stream>>>(
        vents, rels, renc, adj, Wq, Wk, Wv, Wo, l1w, l2w, bq, bk, bv,
        mw, wqkvT, bqkv, woT, l1T, l2T, Qb, Kb, VTb);
    // step 0
    k_attn<<<dim3(16, 16, SK_), 256, 0, stream>>>(Qb, Kb, VTb, mw, partO, partML);
    k_ffn<false><<<M_ / 16, 512, 0, stream>>>(
        partO, partML, woT, bo, l1T, l1b, pra, l2T, l2b, lng, lnb,
        wqkvT + (size_t)384 * 128, bqkv + 384, entl, nullptr, Qb, Kb, VTb);
    // step 1
    k_attn<<<dim3(16, 16, SK_), 256, 0, stream>>>(Qb, Kb, VTb, mw, partO, partML);
    k_ffn<true><<<M_ / 16, 512, 0, stream>>>(
        partO, partML, woT + (size_t)16384, bo + 128,
        l1T + (size_t)65536, l1b + 512, pra + 512,
        l2T + (size_t)65536, l2b + 128, lng + 128, lnb + 128,
        wqkvT, bqkv, entl, gout, Qb, Kb, VTb);
}

// Round 20
// 106.800 us; speedup vs baseline: 1.1572x; 1.0233x over previous
//
#include <hip/hip_runtime.h>
#include <hip/hip_bf16.h>

typedef __bf16 bf16;
typedef __bf16 bf16x4 __attribute__((ext_vector_type(4)));
typedef __bf16 bf16x8 __attribute__((ext_vector_type(8)));
typedef float f32x4 __attribute__((ext_vector_type(4)));
typedef float f32x16 __attribute__((ext_vector_type(16)));

#define B_ 4
#define NE_ 1536
#define NR_ 512
#define N_ 2048
#define D_ 128
#define H_ 4
#define DH_ 32
#define P_ 2
#define M_ (B_*N_)      // 8192 rows total
#define NW_ (N_/32)     // 64 mask words per row
#define SK_ 4           // split-k chunks for attention
#define KCH_ (N_/SK_)   // 512 k per chunk
#define NIT_ (KCH_/64)  // 8 kv-tiles of 64 per chunk

__device__ __forceinline__ f32x4 mfma16(bf16x8 a, bf16x8 b, f32x4 c) {
    return __builtin_amdgcn_mfma_f32_16x16x32_bf16(a, b, c, 0, 0, 0);
}
__device__ __forceinline__ f32x16 mfma32(bf16x8 a, bf16x8 b, f32x16 c) {
    return __builtin_amdgcn_mfma_f32_32x32x16_bf16(a, b, c, 0, 0, 0);
}
__device__ __forceinline__ unsigned cvtpk(float lo, float hi) {
    unsigned r;
    asm("v_cvt_pk_bf16_f32 %0, %1, %2" : "=v"(r) : "v"(lo), "v"(hi));
    return r;
}
__device__ __forceinline__ void swap32(unsigned& a, unsigned& b) {
    asm("v_permlane32_swap_b32 %0, %1" : "+v"(a), "+v"(b));
}
__device__ __forceinline__ void gload16(const void* g, void* l) {
    __builtin_amdgcn_global_load_lds(
        (const __attribute__((address_space(1))) void*)g,
        (__attribute__((address_space(3))) void*)l, 16, 0, 0);
}

// fragment-major weight index: col c (out), k i, depth K.
__device__ __forceinline__ size_t fragidx(int c, int i, int K) {
    int nb = c >> 4, kc = i >> 5;
    int l = ((i >> 3) & 3) * 16 + (c & 15);
    return ((size_t)(nb * (K >> 5) + kc) * 64 + l) * 8 + (i & 7);
}

// ---------------- merged prep: QKV-p0 (direct f32) + mask-pack + repack -----
#define QKVB_ 768                // 128 m-tiles x 6 n-tiles
#define MKN_ (B_*N_*NW_)         // 524288 mask words
#define PPER_ (3*16384 + 16384 + 65536 + 65536 + 384)   // 196992
#define PRN_ (P_*PPER_)          // 393984
__global__ __launch_bounds__(256) void k_prep(
        const float* __restrict__ vents, const int* __restrict__ rels,
        const float* __restrict__ renc, const int* __restrict__ adj,
        const float* __restrict__ Wq, const float* __restrict__ Wk,
        const float* __restrict__ Wv, const float* __restrict__ Wo,
        const float* __restrict__ l1w, const float* __restrict__ l2w,
        const float* __restrict__ bq, const float* __restrict__ bk,
        const float* __restrict__ bv,
        unsigned int* __restrict__ mw,
        bf16* __restrict__ wqkvT, float* __restrict__ bqkv,
        bf16* __restrict__ woT, bf16* __restrict__ l1T,
        bf16* __restrict__ l2T,
        bf16* __restrict__ Qout, bf16* __restrict__ Kout,
        bf16* __restrict__ VTout) {
    const float SC = 0.25503330560513437f;     // (1/sqrt(32)) * log2(e)
    if (blockIdx.x < QKVB_) {
        // ---- QKV projection for step 0, straight from f32 inputs ----
        int qb = blockIdx.x;
        int mt = qb / 6, nt = qb % 6;
        int lane = threadIdx.x & 63, wid = threadIdx.x >> 6;
        int wr = wid >> 1, wc = wid & 1;
        int m0 = mt * 64 + wr * 32;
        int n0 = nt * 64 + wc * 32;
        int lr = lane & 15, lg = lane >> 4;
        const float* srcA[2];
#pragma unroll
        for (int mi = 0; mi < 2; ++mi) {
            int row = m0 + mi * 16 + lr;
            int n = row & (N_ - 1), b = row >> 11;
            srcA[mi] = (n < NE_) ? vents + ((size_t)(b * NE_ + n)) * D_
                                 : renc + (size_t)rels[b * NR_ + (n - NE_)] * D_;
        }
        f32x4 acc[2][2];
#pragma unroll
        for (int mi = 0; mi < 2; ++mi)
#pragma unroll
            for (int ni = 0; ni < 2; ++ni)
                acc[mi][ni] = f32x4{0.f, 0.f, 0.f, 0.f};
        for (int k0 = 0; k0 < 128; k0 += 32) {
            bf16x8 a[2], bb[2];
#pragma unroll
            for (int mi = 0; mi < 2; ++mi) {
                float4 f0 = *(const float4*)(srcA[mi] + k0 + lg * 8);
                float4 f1 = *(const float4*)(srcA[mi] + k0 + lg * 8 + 4);
                bf16x8 v;
                v[0] = (bf16)f0.x; v[1] = (bf16)f0.y; v[2] = (bf16)f0.z; v[3] = (bf16)f0.w;
                v[4] = (bf16)f1.x; v[5] = (bf16)f1.y; v[6] = (bf16)f1.z; v[7] = (bf16)f1.w;
                a[mi] = v;
            }
#pragma unroll
            for (int ni = 0; ni < 2; ++ni) {
                int col = n0 + ni * 16 + lr;
                int which = col >> 7, c0 = col & 127;
                const float* W = which == 0 ? Wq : (which == 1 ? Wk : Wv);
                float sc = which == 0 ? SC : 1.f;
                bf16x8 v;
#pragma unroll
                for (int e = 0; e < 8; ++e)
                    v[e] = (bf16)(W[(size_t)(k0 + lg * 8 + e) * 128 + c0] * sc);
                bb[ni] = v;
            }
#pragma unroll
            for (int mi = 0; mi < 2; ++mi)
#pragma unroll
                for (int ni = 0; ni < 2; ++ni)
                    acc[mi][ni] = mfma16(a[mi], bb[ni], acc[mi][ni]);
        }
#pragma unroll
        for (int mi = 0; mi < 2; ++mi) {
#pragma unroll
            for (int ni = 0; ni < 2; ++ni) {
                int col = n0 + ni * 16 + lr;
                int which = col >> 7, c0 = col & 127;
                float bs = which == 0 ? bq[c0] * SC : (which == 1 ? bk[c0] : bv[c0]);
                int rowb = m0 + mi * 16 + lg * 4;
                if (which == 0) {
#pragma unroll
                    for (int r = 0; r < 4; ++r)
                        Qout[(size_t)(rowb + r) * D_ + c0] = (bf16)(acc[mi][ni][r] + bs);
                } else if (which == 1) {
#pragma unroll
                    for (int r = 0; r < 4; ++r)
                        Kout[(size_t)(rowb + r) * D_ + c0] = (bf16)(acc[mi][ni][r] + bs);
                } else {
                    int h = c0 >> 5, dh = c0 & 31;
                    int b = rowb >> 11, nn = rowb & (N_ - 1);
                    bf16x4 pk;
#pragma unroll
                    for (int r = 0; r < 4; ++r) pk[r] = (bf16)(acc[mi][ni][r] + bs);
                    *(bf16x4*)(VTout + ((size_t)(b * H_ + h) * DH_ + dh) * N_ + nn) = pk;
                }
            }
        }
        return;
    }
    int idx = (blockIdx.x - QKVB_) * 256 + threadIdx.x;
    if (idx < MKN_) {
        const int4* a = (const int4*)(adj + (size_t)idx * 32);
        unsigned int w = 0;
#pragma unroll
        for (int q = 0; q < 8; ++q) {
            int4 t = a[q];
            w |= (t.x != 0 ? 1u : 0u) << (q * 4 + 0);
            w |= (t.y != 0 ? 1u : 0u) << (q * 4 + 1);
            w |= (t.z != 0 ? 1u : 0u) << (q * 4 + 2);
            w |= (t.w != 0 ? 1u : 0u) << (q * 4 + 3);
        }
        mw[idx] = w;
        return;
    }
    idx -= MKN_;
    if (idx >= PRN_) return;
    int p = idx / PPER_;
    int r = idx % PPER_;
    if (r < 3 * 16384) {
        int which = r / 16384, e = r % 16384;
        int o = e >> 7, i = e & 127;
        const float* W = which == 0 ? Wq : (which == 1 ? Wk : Wv);
        float v = W[(size_t)(p * 128 + i) * 128 + o];
        if (which == 0) v *= SC;
        wqkvT[(size_t)p * 384 * 128 + fragidx(which * 128 + o, i, 128)] = (bf16)v;
    } else if ((r -= 3 * 16384) < 16384) {
        int o = r >> 7, i = r & 127;
        woT[(size_t)p * 16384 + fragidx(o, i, 128)] = (bf16)Wo[(size_t)(p * 128 + i) * 128 + o];
    } else if ((r -= 16384) < 65536) {
        int o = r >> 7, i = r & 127;          // o<512, i<128
        l1T[(size_t)p * 65536 + fragidx(o, i, 128)] = (bf16)l1w[(size_t)(p * 128 + i) * 512 + o];
    } else if ((r -= 65536) < 65536) {
        int o = r >> 9, i = r & 511;          // o<128, i<512
        l2T[(size_t)p * 65536 + fragidx(o, i, 512)] = (bf16)l2w[(size_t)(p * 512 + i) * 128 + o];
    } else {
        r -= 65536;
        float v = r < 128 ? bq[p * 128 + r] * SC
                          : (r < 256 ? bk[p * 128 + r - 128] : bv[p * 128 + r - 256]);
        bqkv[p * 384 + r] = v;
    }
}

// ---------------- fused flash attention: ring-3 LDS, padded mask tile -------
// grid (16, 16, SK), block 256 (4 waves); wave: 32 q-rows, 64 k per iter.
// Best-measured configuration (R16, 106.8us): interleaved kb loop, VALU lsum.
__global__ __launch_bounds__(256) void k_attn(
    const bf16* __restrict__ Q, const bf16* __restrict__ Kt,
    const bf16* __restrict__ VT, const unsigned int* __restrict__ mw,
    bf16* __restrict__ partO, float* __restrict__ partML) {
    __shared__ __align__(16) char kbuf[3][4096];   // [slot: m*2+hf][64 k][16B]
    __shared__ __align__(16) char vbuf[3][4096];   // [slot: kt'*2+hf][32 dh][16B]
    __shared__ __align__(16) unsigned mbuf[128][18];   // 9KB mask tile, padded
    int wid = threadIdx.x >> 6;
    int lane = threadIdx.x & 63;
    int ql = lane & 31, hf = lane >> 5;
    int qx = blockIdx.x;
    int bh = blockIdx.y;
    int kc = blockIdx.z;
    int b = bh >> 2, h = bh & 3;
    int qg = qx * 128 + wid * 32 + ql;
    const size_t bnD = (size_t)b * N_ * D_;

    const bf16* qp = Q + bnD + (size_t)qg * D_ + h * 32 + hf * 8;
    bf16x8 qf0 = *(const bf16x8*)(qp);
    bf16x8 qf1 = *(const bf16x8*)(qp + 16);

    // stage this block's 128 q-rows x 16 mask words into LDS
#pragma unroll
    for (int j = 0; j < 2; ++j) {
        int u = threadIdx.x + 256 * j;               // 0..511
        int row = u >> 2, sub = u & 3;
        uint4 mv = *(const uint4*)(mw + ((size_t)b * N_ + qx * 128 + row) * NW_
                                      + kc * (KCH_ / 32) + sub * 4);
        uint2 lo; lo.x = mv.x; lo.y = mv.y;
        uint2 hi; hi.x = mv.z; hi.y = mv.w;
        *(uint2*)(&mbuf[row][sub * 4]) = lo;
        *(uint2*)(&mbuf[row][sub * 4 + 2]) = hi;
    }
    asm volatile("s_waitcnt lgkmcnt(0)" ::: "memory");

    const char* kg = (const char*)(Kt + bnD + (size_t)(kc * KCH_) * D_) + h * 64;
    const char* vg = (const char*)(VT + (size_t)(bh * DH_) * N_ + kc * KCH_);

    f32x16 of;
#pragma unroll
    for (int i = 0; i < 16; ++i) of[i] = 0.f;
    const f32x16 zero16 = of;
    float lsum = 0.f;
    int mrow = wid * 32 + ql;

#define STAGE(bufi, it) do {                                                   \
        int k0s = (it) * 64;                                                   \
        gload16(kg + (size_t)(k0s + lane) * 256 + wid * 16,                    \
                kbuf[bufi] + wid * 1024);                                      \
        gload16(vg + ((size_t)(lane & 31) * N_ + k0s) * 2 +                    \
                    (2 * wid + (lane >> 5)) * 16,                              \
                vbuf[bufi] + wid * 1024);                                      \
    } while (0)

    STAGE(0, 0);
    STAGE(1, 1);
    __builtin_amdgcn_s_barrier();   // mask tile visible to all waves

    unsigned long long mcur = *(const unsigned long long*)(&mbuf[mrow][0]);

#pragma unroll 1
    for (int it = 0; it < NIT_; ++it) {
        int cur = it % 3;
        const char* kb_ = kbuf[cur];
        const char* vb_ = vbuf[cur];
        if (it < NIT_ - 1) asm volatile("s_waitcnt vmcnt(2)" ::: "memory");
        else               asm volatile("s_waitcnt vmcnt(0)" ::: "memory");
        __builtin_amdgcn_s_barrier();
        __builtin_amdgcn_sched_barrier(0);
        if (it + 2 < NIT_) STAGE((it + 2) % 3, it + 2);

        // prefetch next iter's mask words during compute
        unsigned long long mnext = (it + 1 < NIT_)
            ? *(const unsigned long long*)(&mbuf[mrow][(it + 1) * 2]) : 0ull;
        unsigned mw0 = (unsigned)mcur, mw1 = (unsigned)(mcur >> 32);

#pragma unroll
        for (int kb = 0; kb < 2; ++kb) {
            bf16x8 kf0 = *(const bf16x8*)(kb_ + hf * 1024 + (kb * 32 + ql) * 16);
            bf16x8 kf1 = *(const bf16x8*)(kb_ + 2048 + hf * 1024 + (kb * 32 + ql) * 16);
            f32x16 s = mfma32(kf0, qf0, zero16);
            s = mfma32(kf1, qf1, s);

            unsigned wsh = (kb ? mw1 : mw0) >> (hf * 4);
            float p[16];
#pragma unroll
            for (int r = 0; r < 16; ++r) {
                int bitp = (r & 3) + 8 * (r >> 2);
                float e = __builtin_amdgcn_exp2f(s[r]);
                p[r] = ((wsh >> bitp) & 1u) ? e : 0.f;
            }
            float a0 = (p[0] + p[1]) + (p[2] + p[3]);
            float a1 = (p[4] + p[5]) + (p[6] + p[7]);
            float a2 = (p[8] + p[9]) + (p[10] + p[11]);
            float a3 = (p[12] + p[13]) + (p[14] + p[15]);
            lsum += (a0 + a1) + (a2 + a3);

            unsigned lo0 = cvtpk(p[0], p[1]),   hi0 = cvtpk(p[2], p[3]);
            unsigned lo1 = cvtpk(p[4], p[5]),   hi1 = cvtpk(p[6], p[7]);
            unsigned lo2 = cvtpk(p[8], p[9]),   hi2 = cvtpk(p[10], p[11]);
            unsigned lo3 = cvtpk(p[12], p[13]), hi3 = cvtpk(p[14], p[15]);
            swap32(lo0, lo1); swap32(hi0, hi1);
            swap32(lo2, lo3); swap32(hi2, hi3);
            union { unsigned u[4]; bf16x8 v; } f0, f1;
            f0.u[0] = lo0; f0.u[1] = hi0; f0.u[2] = lo1; f0.u[3] = hi1;
            f1.u[0] = lo2; f1.u[1] = hi2; f1.u[2] = lo3; f1.u[3] = hi3;

            bf16x8 va = *(const bf16x8*)(vb_ + ((kb * 2 + 0) * 2 + hf) * 512 + ql * 16);
            bf16x8 vb2 = *(const bf16x8*)(vb_ + ((kb * 2 + 1) * 2 + hf) * 512 + ql * 16);
            __builtin_amdgcn_s_setprio(1);
            of = mfma32(va, f0.v, of);
            of = mfma32(vb2, f1.v, of);
            __builtin_amdgcn_s_setprio(0);
        }
        mcur = mnext;
    }
#undef STAGE

    lsum += __shfl_xor(lsum, 32, 64);
    size_t pb = ((size_t)(kc * 16 + bh) * N_ + qg) * 32;
#pragma unroll
    for (int g = 0; g < 4; ++g) {
        union { unsigned u[2]; bf16x4 v; } pk;
        pk.u[0] = cvtpk(of[4 * g + 0], of[4 * g + 1]);
        pk.u[1] = cvtpk(of[4 * g + 2], of[4 * g + 3]);
        *(bf16x4*)(partO + pb + 8 * g + 4 * hf) = pk.v;
    }
    if (lane < 32)
        partML[(size_t)(kc * 16 + bh) * N_ + qg] = lsum;
}

// ---------------- fused FFN (+ next-step QKV, or final outputs) -------------
// grid M/16 = 512 blocks, 512 threads (8 waves). Block owns 16 rows.
template <bool LAST>
__global__ __launch_bounds__(512) void k_ffn(
        const bf16* __restrict__ partO, const float* __restrict__ partML,
        const bf16* __restrict__ woT, const float* __restrict__ bo,
        const bf16* __restrict__ l1T, const float* __restrict__ l1b,
        const float* __restrict__ pra,
        const bf16* __restrict__ l2T, const float* __restrict__ l2b,
        const float* __restrict__ lng, const float* __restrict__ lnb,
        const bf16* __restrict__ wqkvT2, const float* __restrict__ bqkv2,
        const int* __restrict__ entl, float* __restrict__ gout,
        bf16* __restrict__ Qout, bf16* __restrict__ Kout,
        bf16* __restrict__ VTout) {
    __shared__ __align__(16) char Obuf[16 * 256];    // [16][128] bf16 swz
    __shared__ __align__(16) char Tbuf[16 * 256];    // [16][128] bf16 swz
    __shared__ __align__(16) char Hbuf[16 * 1024];   // [16][512] bf16 swz
    __shared__ float lst[8][16][2];
    int t = threadIdx.x;
    int lane = t & 63, wid = t >> 6;
    int lr = lane & 15, lg = lane >> 4;
    int m0 = blockIdx.x * 16;

    // phase 0: combine split-k attention partials -> Obuf (bf16)
    {
        int i = t >> 5, u = t & 31;          // row i, unit u (h*8 + dh4)
        int r = m0 + i, b = r >> 11, q = r & (N_ - 1);
        int h = u >> 3, dh4 = u & 7;
        int bh = b * 4 + h;
        float L = 0.f;
        f32x4 o = {0.f, 0.f, 0.f, 0.f};
#pragma unroll
        for (int kc = 0; kc < SK_; ++kc) {
            size_t base = (size_t)(kc * 16 + bh) * N_ + q;
            L += partML[base];
            bf16x4 pv = *(const bf16x4*)(partO + base * 32 + dh4 * 4);
#pragma unroll
            for (int j = 0; j < 4; ++j) o[j] += (float)pv[j];
        }
        float rL = 1.f / L;
        bf16x4 pk;
#pragma unroll
        for (int j = 0; j < 4; ++j) pk[j] = (bf16)(o[j] * rL);
        *(bf16x4*)(Obuf + i * 256 + ((u * 8) ^ ((i & 7) << 4))) = pk;
    }
    __syncthreads();

    // phase 1: t = LN(Obuf @ woT + bo) -> Tbuf ; wave wid owns cols wid*16..+16
    float tvx[4];
    {
        f32x4 acc = {0.f, 0.f, 0.f, 0.f};
#pragma unroll
        for (int k0 = 0; k0 < 128; k0 += 32) {
            bf16x8 a = *(const bf16x8*)(Obuf + lr * 256 + (((k0 + lg * 8) * 2) ^ ((lr & 7) << 4)));
            bf16x8 bb = *(const bf16x8*)(woT + ((size_t)(wid * 4 + (k0 >> 5)) * 64 + lane) * 8);
            acc = mfma16(a, bb, acc);
        }
        int col = wid * 16 + lr;
        float bs = bo[col];
#pragma unroll
        for (int r2 = 0; r2 < 4; ++r2) tvx[r2] = acc[r2] + bs;
#pragma unroll
        for (int r2 = 0; r2 < 4; ++r2) {
            float sv = tvx[r2], qv = tvx[r2] * tvx[r2];
#pragma unroll
            for (int msk = 1; msk < 16; msk <<= 1) {
                sv += __shfl_xor(sv, msk, 64);
                qv += __shfl_xor(qv, msk, 64);
            }
            if (lr == 0) { lst[wid][lg * 4 + r2][0] = sv; lst[wid][lg * 4 + r2][1] = qv; }
        }
        __syncthreads();
#pragma unroll
        for (int r2 = 0; r2 < 4; ++r2) {
            int row = lg * 4 + r2;
            float S = 0.f, Q2 = 0.f;
#pragma unroll
            for (int w2 = 0; w2 < 8; ++w2) { S += lst[w2][row][0]; Q2 += lst[w2][row][1]; }
            float mean = S * (1.f / 128.f);
            float var = Q2 * (1.f / 128.f) - mean * mean;
            float rstd = rsqrtf(var + 1e-5f);
            float o = (tvx[r2] - mean) * rstd * lng[col] + lnb[col];
            tvx[r2] = o;
            *(bf16*)(Tbuf + row * 256 + ((col * 2) ^ ((row & 7) << 4))) = (bf16)o;
        }
    }
    __syncthreads();

    // phase 2: h = PReLU(Tbuf @ l1T + l1b) -> Hbuf ; wave owns cols wid*64..+64
    {
        f32x4 acc[4];
#pragma unroll
        for (int ni = 0; ni < 4; ++ni) acc[ni] = f32x4{0.f, 0.f, 0.f, 0.f};
#pragma unroll
        for (int k0 = 0; k0 < 128; k0 += 32) {
            bf16x8 a = *(const bf16x8*)(Tbuf + lr * 256 + (((k0 + lg * 8) * 2) ^ ((lr & 7) << 4)));
#pragma unroll
            for (int ni = 0; ni < 4; ++ni) {
                bf16x8 bb = *(const bf16x8*)(l1T + ((size_t)((wid * 4 + ni) * 4 + (k0 >> 5)) * 64 + lane) * 8);
                acc[ni] = mfma16(a, bb, acc[ni]);
            }
        }
#pragma unroll
        for (int ni = 0; ni < 4; ++ni) {
            int col = wid * 64 + ni * 16 + lr;
            float bs = l1b[col], sl = pra[col];
#pragma unroll
            for (int r2 = 0; r2 < 4; ++r2) {
                int row = lg * 4 + r2;
                float v = acc[ni][r2] + bs;
                v = v >= 0.f ? v : sl * v;
                *(bf16*)(Hbuf + row * 1024 + ((col * 2) ^ ((row & 7) << 4))) = (bf16)v;
            }
        }
    }
    __syncthreads();

    // phase 3: out = LN(Hbuf @ l2T + l2b + t) ; wave owns cols wid*16..+16
    {
        f32x4 acc = {0.f, 0.f, 0.f, 0.f};
#pragma unroll
        for (int k0 = 0; k0 < 512; k0 += 32) {
            bf16x8 a = *(const bf16x8*)(Hbuf + lr * 1024 + (((k0 + lg * 8) * 2) ^ ((lr & 7) << 4)));
            bf16x8 bb = *(const bf16x8*)(l2T + ((size_t)(wid * 16 + (k0 >> 5)) * 64 + lane) * 8);
            acc = mfma16(a, bb, acc);
        }
        int col = wid * 16 + lr;
        float bs = l2b[col];
        float vx[4];
#pragma unroll
        for (int r2 = 0; r2 < 4; ++r2)
            vx[r2] = acc[r2] + bs + tvx[r2];   // resid = f32 t (lane-local)
        __syncthreads();   // lst reuse barrier
#pragma unroll
        for (int r2 = 0; r2 < 4; ++r2) {
            float sv = vx[r2], qv = vx[r2] * vx[r2];
#pragma unroll
            for (int msk = 1; msk < 16; msk <<= 1) {
                sv += __shfl_xor(sv, msk, 64);
                qv += __shfl_xor(qv, msk, 64);
            }
            if (lr == 0) { lst[wid][lg * 4 + r2][0] = sv; lst[wid][lg * 4 + r2][1] = qv; }
        }
        __syncthreads();
#pragma unroll
        for (int r2 = 0; r2 < 4; ++r2) {
            int row = lg * 4 + r2;
            float S = 0.f, Q2 = 0.f;
#pragma unroll
            for (int w2 = 0; w2 < 8; ++w2) { S += lst[w2][row][0]; Q2 += lst[w2][row][1]; }
            float mean = S * (1.f / 128.f);
            float var = Q2 * (1.f / 128.f) - mean * mean;
            float rstd = rsqrtf(var + 1e-5f);
            float o = (vx[r2] - mean) * rstd * lng[col] + lnb[col];
            size_t rowg = (size_t)(m0 + row);
            if (LAST) {
                float* gents = gout + 512;
                gents[rowg * 128 + col] = o;
                int b = (int)(rowg >> 11);
                if ((int)(rowg & (N_ - 1)) == entl[b])
                    gout[b * 128 + col] = o;          // glob
            } else {
                *(bf16*)(Obuf + row * 256 + ((col * 2) ^ ((row & 7) << 4))) = (bf16)o;
            }
        }
        if (LAST && t < 16)
            gout[512 + (size_t)M_ * 128 + m0 + t] = 1.0f;   // emask
    }

    // phase 4 (!LAST): QKV projection of the 16 fresh rows for next prop step
    if (!LAST) {
        __syncthreads();
        f32x4 acc[3];
#pragma unroll
        for (int ni = 0; ni < 3; ++ni) acc[ni] = f32x4{0.f, 0.f, 0.f, 0.f};
#pragma unroll
        for (int k0 = 0; k0 < 128; k0 += 32) {
            bf16x8 a = *(const bf16x8*)(Obuf + lr * 256 + (((k0 + lg * 8) * 2) ^ ((lr & 7) << 4)));
#pragma unroll
            for (int ni = 0; ni < 3; ++ni) {
                bf16x8 bb = *(const bf16x8*)(wqkvT2 + ((size_t)((wid * 3 + ni) * 4 + (k0 >> 5)) * 64 + lane) * 8);
                acc[ni] = mfma16(a, bb, acc[ni]);
            }
        }
#pragma unroll
        for (int ni = 0; ni < 3; ++ni) {
            int col = wid * 48 + ni * 16 + lr;
            float bs = bqkv2[col];
            int rowb = m0 + lg * 4;
            if (col < 128) {
#pragma unroll
                for (int r = 0; r < 4; ++r)
                    Qout[(size_t)(rowb + r) * D_ + col] = (bf16)(acc[ni][r] + bs);
            } else if (col < 256) {
#pragma unroll
                for (int r = 0; r < 4; ++r)
                    Kout[(size_t)(rowb + r) * D_ + (col - 128)] = (bf16)(acc[ni][r] + bs);
            } else {
                int d = col - 256, h = d >> 5, dh = d & 31;
                int b = rowb >> 11, nn = rowb & (N_ - 1);
                bf16x4 pk;
#pragma unroll
                for (int r = 0; r < 4; ++r) pk[r] = (bf16)(acc[ni][r] + bs);
                *(bf16x4*)(VTout + ((size_t)(b * H_ + h) * DH_ + dh) * N_ + nn) = pk;
            }
        }
    }
}

extern "C" void kernel_launch(void* const* d_in, const int* in_sizes, int n_in,
                              void* d_out, int out_size, void* d_ws, size_t ws_size,
                              hipStream_t stream) {
    const float* vents = (const float*)d_in[0];
    const int*   rels  = (const int*)d_in[1];
    const int*   adj   = (const int*)d_in[2];
    const int*   entl  = (const int*)d_in[3];
    const float* renc  = (const float*)d_in[4];
    const float* Wq = (const float*)d_in[5];
    const float* bq = (const float*)d_in[6];
    const float* Wk = (const float*)d_in[7];
    const float* bk = (const float*)d_in[8];
    const float* Wv = (const float*)d_in[9];
    const float* bv = (const float*)d_in[10];
    const float* Wo = (const float*)d_in[11];
    const float* bo = (const float*)d_in[12];
    const float* l1w = (const float*)d_in[13];
    const float* l1b = (const float*)d_in[14];
    const float* l2w = (const float*)d_in[15];
    const float* l2b = (const float*)d_in[16];
    const float* lng = (const float*)d_in[17];
    const float* lnb = (const float*)d_in[18];
    const float* pra = (const float*)d_in[19];

    char* w = (char*)d_ws;
    auto alloc = [&](size_t bytes) { char* r = w; w += (bytes + 255) & ~(size_t)255; return r; };
    unsigned int* mw = (unsigned int*)alloc((size_t)B_ * N_ * NW_ * 4);
    bf16*  wqkvT = (bf16*)alloc((size_t)P_ * 384 * 128 * 2);
    float* bqkv  = (float*)alloc((size_t)P_ * 384 * 4);
    bf16*  woT   = (bf16*)alloc((size_t)P_ * 128 * 128 * 2);
    bf16*  l1T   = (bf16*)alloc((size_t)P_ * 512 * 128 * 2);
    bf16*  l2T   = (bf16*)alloc((size_t)P_ * 128 * 512 * 2);
    bf16*  Qb    = (bf16*)alloc((size_t)M_ * D_ * 2);
    bf16*  Kb    = (bf16*)alloc((size_t)M_ * D_ * 2);
    bf16*  VTb   = (bf16*)alloc((size_t)M_ * D_ * 2);
    bf16*  partO  = (bf16*)alloc((size_t)SK_ * 16 * N_ * 32 * 2);    // 8 MiB
    float* partML = (float*)alloc((size_t)SK_ * 16 * N_ * 4);        // 0.5 MiB
    float* gout  = (float*)d_out;

    const int PRB = QKVB_ + (MKN_ + PRN_ + 255) / 256;
    k_prep<<<PRB, 256, 0, stream>>>(
        vents, rels, renc, adj, Wq, Wk, Wv, Wo, l1w, l2w, bq, bk, bv,
        mw, wqkvT, bqkv, woT, l1T, l2T, Qb, Kb, VTb);
    // step 0
    k_attn<<<dim3(16, 16, SK_), 256, 0, stream>>>(Qb, Kb, VTb, mw, partO, partML);
    k_ffn<false><<<M_ / 16, 512, 0, stream>>>(
        partO, partML, woT, bo, l1T, l1b, pra, l2T, l2b, lng, lnb,
        wqkvT + (size_t)384 * 128, bqkv + 384, entl, nullptr, Qb, Kb, VTb);
    // step 1
    k_attn<<<dim3(16, 16, SK_), 256, 0, stream>>>(Qb, Kb, VTb, mw, partO, partML);
    k_ffn<true><<<M_ / 16, 512, 0, stream>>>(
        partO, partML, woT + (size_t)16384, bo + 128,
        l1T + (size_t)65536, l1b + 512, pra + 512,
        l2T + (size_t)65536, l2b + 128, lng + 128, lnb + 128,
        wqkvT, bqkv, entl, gout, Qb, Kb, VTb);
}